// Round 1
// baseline (102.834 us; speedup 1.0000x reference)
//
#include <hip/hip_runtime.h>

// Causal linear attention (ELU+1 feature map), B=2 S=2048 H=16 D=64.
// out[b,t,h,:] = (phi(q)[t] . Sum_{s<=t} phi(k)[s] v[s]^T) / (phi(q)[t] . Sum_{s<=t} phi(k)[s])
// Chunked: per-chunk states + exclusive scan + per-chunk output (inter via state, intra quadratic).

#define BB 2
#define SS 2048
#define HH 16
#define DD 64
#define CC 128                 // chunk length
#define NC (SS / CC)           // 16 chunks per (b,h)
#define BH (BB * HH)           // 32
#define NCHUNK (BH * NC)       // 512
#define STSZ (DD * DD + DD)    // 4160 floats per chunk state (KV + kz)

__device__ __forceinline__ float phi(float x) {
    return x > 0.f ? x + 1.f : __expf(x);
}

__device__ __forceinline__ unsigned short f2bf(float x) {
    unsigned int u = __float_as_uint(x);
    u += 0x7fffu + ((u >> 16) & 1u);   // round-to-nearest-even
    return (unsigned short)(u >> 16);
}

__device__ __forceinline__ void decode8(uint4 u, float* f) {
    f[0] = __uint_as_float(u.x << 16); f[1] = __uint_as_float(u.x & 0xffff0000u);
    f[2] = __uint_as_float(u.y << 16); f[3] = __uint_as_float(u.y & 0xffff0000u);
    f[4] = __uint_as_float(u.z << 16); f[5] = __uint_as_float(u.z & 0xffff0000u);
    f[6] = __uint_as_float(u.w << 16); f[7] = __uint_as_float(u.w & 0xffff0000u);
}

// ---------------- Kernel 1: per-chunk states (fp32) ----------------
__global__ __launch_bounds__(256, 2)
void chunk_state(const float* __restrict__ qk, const float* __restrict__ v,
                 float* __restrict__ st) {
    __shared__ float kb[CC][DD];   // phi(k) chunk
    __shared__ float vb[CC][DD];   // v chunk

    const int tid = threadIdx.x;
    const int blk = blockIdx.x;
    const int bh = blk / NC, c = blk % NC;
    const int b = bh / HH, h = bh % HH;
    const int s0 = c * CC;

    const int lr = tid >> 4;            // 0..15
    const int lc = (tid & 15) * 4;      // 0..60
    #pragma unroll
    for (int it = 0; it < 8; ++it) {
        int row = it * 16 + lr;
        size_t ka = ((size_t)((b * SS + s0 + row) * 2 + 1)) * (HH * DD) + h * DD + lc;
        float4 kv = *(const float4*)(qk + ka);
        kb[row][lc + 0] = phi(kv.x); kb[row][lc + 1] = phi(kv.y);
        kb[row][lc + 2] = phi(kv.z); kb[row][lc + 3] = phi(kv.w);
        size_t va = ((size_t)((b * SS + s0 + row) * HH + h)) * DD + lc;
        *(float4*)&vb[row][lc] = *(const float4*)(v + va);
    }
    __syncthreads();

    const int d0 = (tid >> 4) * 4;      // 0..60
    const int e0 = (tid & 15) * 4;      // 0..60
    float a[4][4];
    #pragma unroll
    for (int r = 0; r < 4; ++r)
        #pragma unroll
        for (int e = 0; e < 4; ++e) a[r][e] = 0.f;

    #pragma unroll 4
    for (int s = 0; s < CC; ++s) {
        float4 kk = *(const float4*)&kb[s][d0];
        float4 vv = *(const float4*)&vb[s][e0];
        float kr[4] = {kk.x, kk.y, kk.z, kk.w};
        float vr[4] = {vv.x, vv.y, vv.z, vv.w};
        #pragma unroll
        for (int r = 0; r < 4; ++r)
            #pragma unroll
            for (int e = 0; e < 4; ++e)
                a[r][e] = fmaf(kr[r], vr[e], a[r][e]);
    }

    float* o = st + (size_t)blk * STSZ;
    #pragma unroll
    for (int r = 0; r < 4; ++r) {
        float4 w4 = make_float4(a[r][0], a[r][1], a[r][2], a[r][3]);
        *(float4*)(o + (d0 + r) * DD + e0) = w4;
    }
    if (tid < DD) {
        float z = 0.f;
        #pragma unroll 4
        for (int s = 0; s < CC; ++s) z += kb[s][tid];
        o[DD * DD + tid] = z;
    }
}

// ---------------- Kernel 2: exclusive prefix over chunks ----------------
__global__ __launch_bounds__(256)
void chunk_scan(float* __restrict__ st) {
    const int bh = blockIdx.x;
    const size_t base = (size_t)bh * NC * STSZ;
    for (int i = threadIdx.x; i < STSZ; i += 256) {
        float run = 0.f;
        #pragma unroll
        for (int c = 0; c < NC; ++c) {
            size_t idx = base + (size_t)c * STSZ + i;
            float x = st[idx];
            st[idx] = run;
            run += x;
        }
    }
}

// ---------------- Kernel 3: per-chunk output ----------------
__global__ __launch_bounds__(256, 1)
void lin_attn_out(const float* __restrict__ qk, const float* __restrict__ v,
                  const float* __restrict__ st, float* __restrict__ out) {
    __shared__ __align__(16) unsigned short Qt[DD][CC];  // [d][t] bf16(phi(q))  16KB
    __shared__ __align__(16) unsigned short Kt[DD][CC];  // [d][s] bf16(phi(k))  16KB
    __shared__ __align__(16) unsigned short Vb[CC][DD];  // [s][e] bf16(v)       16KB
    __shared__ __align__(16) float Wt[CC][CC];           // [s][t] masked scores 64KB
    __shared__ __align__(16) float S0l[DD][DD];          // prefix KV            16KB
    __shared__ float kzl[DD];

    const int tid = threadIdx.x;
    const int blk = blockIdx.x;
    const int bh = blk / NC, c = blk % NC;
    const int b = bh / HH, h = bh % HH;
    const int s0 = c * CC;

    // ---- stage inputs ----
    const int lr = tid >> 4;
    const int lc = (tid & 15) * 4;
    #pragma unroll
    for (int it = 0; it < 8; ++it) {
        int row = it * 16 + lr;
        size_t qa = ((size_t)((b * SS + s0 + row) * 2 + 0)) * (HH * DD) + h * DD + lc;
        float4 qv = *(const float4*)(qk + qa);
        float4 kv = *(const float4*)(qk + qa + HH * DD);
        Qt[lc + 0][row] = f2bf(phi(qv.x)); Qt[lc + 1][row] = f2bf(phi(qv.y));
        Qt[lc + 2][row] = f2bf(phi(qv.z)); Qt[lc + 3][row] = f2bf(phi(qv.w));
        Kt[lc + 0][row] = f2bf(phi(kv.x)); Kt[lc + 1][row] = f2bf(phi(kv.y));
        Kt[lc + 2][row] = f2bf(phi(kv.z)); Kt[lc + 3][row] = f2bf(phi(kv.w));
        size_t va = ((size_t)((b * SS + s0 + row) * HH + h)) * DD + lc;
        float4 vv = *(const float4*)(v + va);
        unsigned int p0 = (unsigned int)f2bf(vv.x) | ((unsigned int)f2bf(vv.y) << 16);
        unsigned int p1 = (unsigned int)f2bf(vv.z) | ((unsigned int)f2bf(vv.w) << 16);
        *(uint2*)&Vb[row][lc] = make_uint2(p0, p1);
    }
    const float* stc = st + (size_t)blk * STSZ;
    {
        float* s0f = &S0l[0][0];
        #pragma unroll
        for (int it = 0; it < 4; ++it) {
            int idx = it * 1024 + tid * 4;
            *(float4*)(s0f + idx) = *(const float4*)(stc + idx);
        }
        if (tid < DD) kzl[tid] = stc[DD * DD + tid];
    }
    __syncthreads();

    // ---- phase A: W = phi(Q) phi(K)^T, causal-masked, into Wt[s][t] ----
    {
        const int ti = (tid & 15) * 8;   // t block
        const int sj = (tid >> 4) * 8;   // s block
        float w[8][8];
        #pragma unroll
        for (int r = 0; r < 8; ++r)
            #pragma unroll
            for (int q8 = 0; q8 < 8; ++q8) w[r][q8] = 0.f;

        #pragma unroll 2
        for (int d = 0; d < DD; ++d) {
            uint4 qw = *(const uint4*)&Qt[d][ti];
            uint4 kw = *(const uint4*)&Kt[d][sj];
            float qd[8], kd[8];
            decode8(qw, qd); decode8(kw, kd);
            #pragma unroll
            for (int r = 0; r < 8; ++r)
                #pragma unroll
                for (int q8 = 0; q8 < 8; ++q8)
                    w[r][q8] = fmaf(qd[r], kd[q8], w[r][q8]);
        }
        #pragma unroll
        for (int q8 = 0; q8 < 8; ++q8) {
            int s = sj + q8;
            float4 lo, hi;
            lo.x = (s <= ti + 0) ? w[0][q8] : 0.f;
            lo.y = (s <= ti + 1) ? w[1][q8] : 0.f;
            lo.z = (s <= ti + 2) ? w[2][q8] : 0.f;
            lo.w = (s <= ti + 3) ? w[3][q8] : 0.f;
            hi.x = (s <= ti + 4) ? w[4][q8] : 0.f;
            hi.y = (s <= ti + 5) ? w[5][q8] : 0.f;
            hi.z = (s <= ti + 6) ? w[6][q8] : 0.f;
            hi.w = (s <= ti + 7) ? w[7][q8] : 0.f;
            *(float4*)&Wt[s][ti] = lo;
            *(float4*)&Wt[s][ti + 4] = hi;
        }
    }
    __syncthreads();

    // ---- phase B: out = (Q.S0 + W_masked.V) / (Q.kz + rowsum(W)) ----
    {
        const int e0 = (tid & 15) * 4;   // 0..60
        const int t0 = (tid >> 4) * 8;   // 0..120
        float acc[8][4];
        float nu[8];
        #pragma unroll
        for (int r = 0; r < 8; ++r) {
            nu[r] = 0.f;
            #pragma unroll
            for (int e = 0; e < 4; ++e) acc[r][e] = 0.f;
        }
        #pragma unroll 2
        for (int d = 0; d < DD; ++d) {
            uint4 qw = *(const uint4*)&Qt[d][t0];
            float qd[8];
            decode8(qw, qd);
            float4 sv = *(const float4*)&S0l[d][e0];
            float svr[4] = {sv.x, sv.y, sv.z, sv.w};
            float kzd = kzl[d];
            #pragma unroll
            for (int r = 0; r < 8; ++r) {
                nu[r] = fmaf(qd[r], kzd, nu[r]);
                #pragma unroll
                for (int e = 0; e < 4; ++e)
                    acc[r][e] = fmaf(qd[r], svr[e], acc[r][e]);
            }
        }
        #pragma unroll 2
        for (int s = 0; s < CC; ++s) {
            float4 wlo = *(const float4*)&Wt[s][t0];
            float4 whi = *(const float4*)&Wt[s][t0 + 4];
            float w8[8] = {wlo.x, wlo.y, wlo.z, wlo.w, whi.x, whi.y, whi.z, whi.w};
            uint2 vw = *(const uint2*)&Vb[s][e0];
            float vv[4];
            vv[0] = __uint_as_float(vw.x << 16); vv[1] = __uint_as_float(vw.x & 0xffff0000u);
            vv[2] = __uint_as_float(vw.y << 16); vv[3] = __uint_as_float(vw.y & 0xffff0000u);
            #pragma unroll
            for (int r = 0; r < 8; ++r) {
                nu[r] += w8[r];
                #pragma unroll
                for (int e = 0; e < 4; ++e)
                    acc[r][e] = fmaf(w8[r], vv[e], acc[r][e]);
            }
        }
        #pragma unroll
        for (int r = 0; r < 8; ++r) {
            int t = t0 + r;
            float inv = 1.f / nu[r];
            float4 o = make_float4(acc[r][0] * inv, acc[r][1] * inv,
                                   acc[r][2] * inv, acc[r][3] * inv);
            size_t oa = ((size_t)((b * SS + s0 + t) * HH + h)) * DD + e0;
            *(float4*)(out + oa) = o;
        }
    }
}

extern "C" void kernel_launch(void* const* d_in, const int* in_sizes, int n_in,
                              void* d_out, int out_size, void* d_ws, size_t ws_size,
                              hipStream_t stream) {
    const float* qk = (const float*)d_in[0];
    const float* v  = (const float*)d_in[1];
    float* out = (float*)d_out;
    float* st  = (float*)d_ws;   // NCHUNK * STSZ floats = ~8.5 MB

    chunk_state<<<NCHUNK, 256, 0, stream>>>(qk, v, st);
    chunk_scan<<<BH, 256, 0, stream>>>(st);
    lin_attn_out<<<NCHUNK, 256, 0, stream>>>(qk, v, st, out);
}

// Round 2
// 39.392 us; speedup vs baseline: 2.6106x; 2.6106x over previous
//
#include <hip/hip_runtime.h>

// Causal linear attention (ELU+1), B=2 S=2048 H=16 D=64, chunked C=128.
// K1: per-chunk states (fp32 VALU).  K2: exclusive chunk scan (parallel).
// K3: per-chunk output via bf16 MFMA (QK^T, W·V, Q·S0), nu via rowsums.

#define BB 2
#define SS 2048
#define HH 16
#define DD 64
#define CC 128
#define NC (SS / CC)           // 16
#define BH (BB * HH)           // 32
#define NCHUNK (BH * NC)       // 512
#define STSZ (DD * DD + DD)    // 4160

typedef __attribute__((ext_vector_type(8))) short bf16x8;
typedef __attribute__((ext_vector_type(4))) float f32x4;

__device__ __forceinline__ float phi(float x) {
    return x > 0.f ? x + 1.f : __expf(x);
}
__device__ __forceinline__ unsigned short f2bf(float x) {
    unsigned int u = __float_as_uint(x);
    u += 0x7fffu + ((u >> 16) & 1u);   // RNE
    return (unsigned short)(u >> 16);
}
__device__ __forceinline__ float bf2f(unsigned short b) {
    return __uint_as_float(((unsigned int)b) << 16);
}

// ---------------- Kernel 1: per-chunk states (fp32) ----------------
__global__ __launch_bounds__(256, 2)
void chunk_state(const float* __restrict__ qk, const float* __restrict__ v,
                 float* __restrict__ st) {
    __shared__ float kb[CC][DD];
    __shared__ float vb[CC][DD];

    const int tid = threadIdx.x;
    const int blk = blockIdx.x;
    const int bh = blk / NC, c = blk % NC;
    const int b = bh / HH, h = bh % HH;
    const int s0 = c * CC;

    const int lr = tid >> 4;
    const int lc = (tid & 15) * 4;
    #pragma unroll
    for (int it = 0; it < 8; ++it) {
        int row = it * 16 + lr;
        size_t ka = ((size_t)((b * SS + s0 + row) * 2 + 1)) * (HH * DD) + h * DD + lc;
        float4 kv = *(const float4*)(qk + ka);
        kb[row][lc + 0] = phi(kv.x); kb[row][lc + 1] = phi(kv.y);
        kb[row][lc + 2] = phi(kv.z); kb[row][lc + 3] = phi(kv.w);
        size_t va = ((size_t)((b * SS + s0 + row) * HH + h)) * DD + lc;
        *(float4*)&vb[row][lc] = *(const float4*)(v + va);
    }
    __syncthreads();

    const int d0 = (tid >> 4) * 4;
    const int e0 = (tid & 15) * 4;
    float a[4][4];
    #pragma unroll
    for (int r = 0; r < 4; ++r)
        #pragma unroll
        for (int e = 0; e < 4; ++e) a[r][e] = 0.f;

    #pragma unroll 4
    for (int s = 0; s < CC; ++s) {
        float4 kk = *(const float4*)&kb[s][d0];
        float4 vv = *(const float4*)&vb[s][e0];
        float kr[4] = {kk.x, kk.y, kk.z, kk.w};
        float vr[4] = {vv.x, vv.y, vv.z, vv.w};
        #pragma unroll
        for (int r = 0; r < 4; ++r)
            #pragma unroll
            for (int e = 0; e < 4; ++e)
                a[r][e] = fmaf(kr[r], vr[e], a[r][e]);
    }

    float* o = st + (size_t)blk * STSZ;
    #pragma unroll
    for (int r = 0; r < 4; ++r)
        *(float4*)(o + (d0 + r) * DD + e0) = make_float4(a[r][0], a[r][1], a[r][2], a[r][3]);
    if (tid < DD) {
        float z = 0.f;
        #pragma unroll 4
        for (int s = 0; s < CC; ++s) z += kb[s][tid];
        o[DD * DD + tid] = z;
    }
}

// ---------------- Kernel 2: exclusive prefix over chunks (parallel) ----------------
__global__ __launch_bounds__(256)
void chunk_scan(float* __restrict__ st) {
    const int bh = blockIdx.x / 17;
    const int i = (blockIdx.x % 17) * 256 + threadIdx.x;
    if (i >= STSZ) return;
    size_t base = (size_t)bh * NC * STSZ + i;
    float run = 0.f;
    #pragma unroll
    for (int c = 0; c < NC; ++c) {
        float x = st[base + (size_t)c * STSZ];
        st[base + (size_t)c * STSZ] = run;
        run += x;
    }
}

// ---------------- Kernel 3: per-chunk output via MFMA ----------------
__global__ __launch_bounds__(256, 2)
void lin_attn_out(const float* __restrict__ qk, const float* __restrict__ v,
                  const float* __restrict__ st, float* __restrict__ out) {
    __shared__ __align__(16) unsigned short Qb[CC][72];    // [t][d] bf16 phi(q)  18.4KB
    __shared__ __align__(16) unsigned short Kb[CC][72];    // [s][d] bf16 phi(k)  18.4KB
    __shared__ __align__(16) unsigned short Vt[DD][136];   // [e][s] bf16 v^T     17.4KB
    __shared__ __align__(16) unsigned short S0l[DD][72];   // [e][d] bf16 S0^T     9.2KB
    __shared__ float kzl[DD];
    __shared__ __align__(16) unsigned short Wl[4][32][40]; // per-wave S bounce   10.2KB
    __shared__ float nul[4][32];

    const int tid = threadIdx.x;
    const int blk = blockIdx.x;
    const int bh = blk / NC, c = blk % NC;
    const int b = bh / HH, h = bh % HH;
    const int s0 = c * CC;

    // ---- stage ----
    const int lr = tid >> 4;
    const int lc = (tid & 15) * 4;
    #pragma unroll
    for (int it = 0; it < 8; ++it) {
        int row = it * 16 + lr;
        size_t qa = ((size_t)((b * SS + s0 + row) * 2 + 0)) * (HH * DD) + h * DD + lc;
        float4 qv = *(const float4*)(qk + qa);
        float4 kv = *(const float4*)(qk + qa + HH * DD);
        *(ushort4*)&Qb[row][lc] = make_ushort4(f2bf(phi(qv.x)), f2bf(phi(qv.y)),
                                               f2bf(phi(qv.z)), f2bf(phi(qv.w)));
        *(ushort4*)&Kb[row][lc] = make_ushort4(f2bf(phi(kv.x)), f2bf(phi(kv.y)),
                                               f2bf(phi(kv.z)), f2bf(phi(kv.w)));
        size_t va = ((size_t)((b * SS + s0 + row) * HH + h)) * DD + lc;
        float4 vv = *(const float4*)(v + va);
        Vt[lc + 0][row] = f2bf(vv.x);
        Vt[lc + 1][row] = f2bf(vv.y);
        Vt[lc + 2][row] = f2bf(vv.z);
        Vt[lc + 3][row] = f2bf(vv.w);
    }
    const float* stc = st + (size_t)blk * STSZ;
    #pragma unroll
    for (int it = 0; it < 4; ++it) {
        int idx = it * 1024 + tid * 4;
        float4 sv = *(const float4*)(stc + idx);
        int d = idx >> 6, e = idx & 63;
        S0l[e + 0][d] = f2bf(sv.x);
        S0l[e + 1][d] = f2bf(sv.y);
        S0l[e + 2][d] = f2bf(sv.z);
        S0l[e + 3][d] = f2bf(sv.w);
    }
    if (tid < DD) kzl[tid] = stc[DD * DD + tid];
    __syncthreads();

    // ---- per-wave MFMA ----
    const int w = tid >> 6;        // wave id, t-band [32w, 32w+32)
    const int lane = tid & 63;
    const int g = lane >> 4;       // 0..3
    const int ln = lane & 15;

    bf16x8 aq[2][2];
    #pragma unroll
    for (int m = 0; m < 2; ++m)
        #pragma unroll
        for (int kb2 = 0; kb2 < 2; ++kb2)
            aq[m][kb2] = *(const bf16x8*)&Qb[w * 32 + m * 16 + ln][kb2 * 32 + g * 8];

    f32x4 O[2][4];
    #pragma unroll
    for (int m = 0; m < 2; ++m)
        #pragma unroll
        for (int n = 0; n < 4; ++n) O[m][n] = (f32x4){0.f, 0.f, 0.f, 0.f};

    // inter-chunk: O += Q * S0   (B-frag from S0^T in LDS)
    #pragma unroll
    for (int n = 0; n < 4; ++n) {
        bf16x8 b0 = *(const bf16x8*)&S0l[n * 16 + ln][g * 8];
        bf16x8 b1 = *(const bf16x8*)&S0l[n * 16 + ln][32 + g * 8];
        #pragma unroll
        for (int m = 0; m < 2; ++m) {
            O[m][n] = __builtin_amdgcn_mfma_f32_16x16x32_bf16(aq[m][0], b0, O[m][n], 0, 0, 0);
            O[m][n] = __builtin_amdgcn_mfma_f32_16x16x32_bf16(aq[m][1], b1, O[m][n], 0, 0, 0);
        }
    }

    // nu base: q . kz  (A-layout, t = 16m+ln, partial over this lane's d-octets)
    float nuA[2] = {0.f, 0.f};
    #pragma unroll
    for (int kb2 = 0; kb2 < 2; ++kb2)
        #pragma unroll
        for (int j = 0; j < 8; ++j) {
            float kzv = kzl[kb2 * 32 + g * 8 + j];
            nuA[0] = fmaf(bf2f((unsigned short)aq[0][kb2][j]), kzv, nuA[0]);
            nuA[1] = fmaf(bf2f((unsigned short)aq[1][kb2][j]), kzv, nuA[1]);
        }

    // causal s-block loop
    for (int sblk = 0; sblk <= w; ++sblk) {
        const bool diag = (sblk == w);
        f32x4 Sc[2][2];
        #pragma unroll
        for (int m = 0; m < 2; ++m)
            #pragma unroll
            for (int ns = 0; ns < 2; ++ns) Sc[m][ns] = (f32x4){0.f, 0.f, 0.f, 0.f};

        #pragma unroll
        for (int ns = 0; ns < 2; ++ns) {
            int s = sblk * 32 + ns * 16 + ln;
            bf16x8 bk0 = *(const bf16x8*)&Kb[s][g * 8];
            bf16x8 bk1 = *(const bf16x8*)&Kb[s][32 + g * 8];
            #pragma unroll
            for (int m = 0; m < 2; ++m) {
                Sc[m][ns] = __builtin_amdgcn_mfma_f32_16x16x32_bf16(aq[m][0], bk0, Sc[m][ns], 0, 0, 0);
                Sc[m][ns] = __builtin_amdgcn_mfma_f32_16x16x32_bf16(aq[m][1], bk1, Sc[m][ns], 0, 0, 0);
            }
        }

        // mask + bounce S (f32 C-layout -> bf16 A-layout via LDS)
        #pragma unroll
        for (int m = 0; m < 2; ++m)
            #pragma unroll
            for (int ns = 0; ns < 2; ++ns)
                #pragma unroll
                for (int r = 0; r < 4; ++r) {
                    int t_loc = m * 16 + g * 4 + r;
                    int s_loc = ns * 16 + ln;
                    float val = Sc[m][ns][r];
                    if (diag && s_loc > t_loc) val = 0.f;
                    Wl[w][t_loc][s_loc] = f2bf(val);
                }
        asm volatile("s_waitcnt lgkmcnt(0)" ::: "memory");
        __builtin_amdgcn_sched_barrier(0);

        bf16x8 bv[4];
        #pragma unroll
        for (int n = 0; n < 4; ++n)
            bv[n] = *(const bf16x8*)&Vt[n * 16 + ln][sblk * 32 + g * 8];

        #pragma unroll
        for (int m = 0; m < 2; ++m) {
            bf16x8 pa = *(const bf16x8*)&Wl[w][m * 16 + ln][g * 8];
            float rs = 0.f;
            #pragma unroll
            for (int j = 0; j < 8; ++j) rs += bf2f((unsigned short)pa[j]);
            nuA[m] += rs;
            #pragma unroll
            for (int n = 0; n < 4; ++n)
                O[m][n] = __builtin_amdgcn_mfma_f32_16x16x32_bf16(pa, bv[n], O[m][n], 0, 0, 0);
        }
    }

    // nu: reduce partials over the 4 lane-groups, redistribute to C-layout
    #pragma unroll
    for (int m = 0; m < 2; ++m) {
        float nt = nuA[m];
        nt += __shfl_xor(nt, 16);
        nt += __shfl_xor(nt, 32);
        if (g == 0) nul[w][m * 16 + ln] = nt;
    }
    asm volatile("s_waitcnt lgkmcnt(0)" ::: "memory");
    __builtin_amdgcn_sched_barrier(0);

    #pragma unroll
    for (int m = 0; m < 2; ++m) {
        float inv[4];
        #pragma unroll
        for (int r = 0; r < 4; ++r) inv[r] = 1.f / nul[w][m * 16 + g * 4 + r];
        #pragma unroll
        for (int n = 0; n < 4; ++n)
            #pragma unroll
            for (int r = 0; r < 4; ++r) {
                int t = w * 32 + m * 16 + g * 4 + r;
                int e = n * 16 + ln;
                size_t oa = ((size_t)((b * SS + s0 + t) * HH + h)) * DD + e;
                out[oa] = O[m][n][r] * inv[r];
            }
    }
}

extern "C" void kernel_launch(void* const* d_in, const int* in_sizes, int n_in,
                              void* d_out, int out_size, void* d_ws, size_t ws_size,
                              hipStream_t stream) {
    const float* qk = (const float*)d_in[0];
    const float* v  = (const float*)d_in[1];
    float* outp = (float*)d_out;
    float* st   = (float*)d_ws;

    chunk_state<<<NCHUNK, 256, 0, stream>>>(qk, v, st);
    chunk_scan<<<BH * 17, 256, 0, stream>>>(st);
    lin_attn_out<<<NCHUNK, 256, 0, stream>>>(qk, v, st, outp);
}

// Round 3
// 33.665 us; speedup vs baseline: 3.0546x; 1.1701x over previous
//
#include <hip/hip_runtime.h>

// Causal linear attention (ELU+1), B=2 S=2048 H=16 D=64, chunk C=128.
// K1 prep_state: bf16 phi(k)/v^T export (swizzled) + per-chunk KV^T & kz via MFMA.
// K2 chunk_scan: exclusive prefix over chunks -> bf16 S0^T (swizzled) + fp32 kz.
// K3 lin_attn_out: global_load_lds staging, q->regs, MFMA QK^T / W.V / Q.S0.

#define BB 2
#define SS 2048
#define HH 16
#define DD 64
#define CC 128
#define NC (SS / CC)           // 16
#define BH (BB * HH)           // 32
#define NCHUNK (BH * NC)       // 512
#define STSZ (DD * DD + DD)    // 4160

// ws layout (bytes)
#define WS_KB (512LL * 4160 * 4)            // after st fp32: 8,519,680
#define WS_VT (WS_KB + 512LL * 16384)
#define WS_S0 (WS_VT + 512LL * 16384)
#define WS_KZ (WS_S0 + 512LL * 8192)

typedef __attribute__((ext_vector_type(8))) short bf16x8;
typedef __attribute__((ext_vector_type(4))) float f32x4;

__device__ __forceinline__ float phi(float x) {
    return x > 0.f ? x + 1.f : __expf(x);
}
__device__ __forceinline__ unsigned short f2bf(float x) {
    unsigned int u = __float_as_uint(x);
    u += 0x7fffu + ((u >> 16) & 1u);
    return (unsigned short)(u >> 16);
}
__device__ __forceinline__ float bf2f(unsigned short b) {
    return __uint_as_float(((unsigned int)b) << 16);
}
__device__ __forceinline__ void gload16(const void* g, void* lds) {
    __builtin_amdgcn_global_load_lds(
        (const __attribute__((address_space(1))) unsigned int*)g,
        (__attribute__((address_space(3))) unsigned int*)lds, 16, 0, 0);
}

// ---------------- Kernel 1 ----------------
__global__ __launch_bounds__(256, 2)
void prep_state(const float* __restrict__ qk, const float* __restrict__ v,
                float* __restrict__ st, unsigned short* __restrict__ kbg,
                unsigned short* __restrict__ vtg) {
    __shared__ unsigned short Kt[DD][136];   // [d][s] phi(k)
    __shared__ unsigned short Vt[DD][136];   // [e][s] v

    const int tid = threadIdx.x, blk = blockIdx.x;
    const int bh = blk / NC, c = blk % NC, b = bh / HH, h = bh % HH;
    const int s0 = c * CC;
    const int lr = tid >> 4, lc = (tid & 15) * 4;
    char* kbc = (char*)kbg + (size_t)blk * 16384;

    #pragma unroll
    for (int it = 0; it < 8; ++it) {
        int row = it * 16 + lr;
        size_t ka = ((size_t)((b * SS + s0 + row) * 2 + 1)) * (HH * DD) + h * DD + lc;
        float4 kv = *(const float4*)(qk + ka);
        unsigned short k0 = f2bf(phi(kv.x)), k1 = f2bf(phi(kv.y));
        unsigned short k2 = f2bf(phi(kv.z)), k3 = f2bf(phi(kv.w));
        *(ushort4*)(kbc + row * 128 + ((lc * 2) ^ ((row & 7) << 4))) = make_ushort4(k0, k1, k2, k3);
        Kt[lc + 0][row] = k0; Kt[lc + 1][row] = k1;
        Kt[lc + 2][row] = k2; Kt[lc + 3][row] = k3;
        size_t va = ((size_t)((b * SS + s0 + row) * HH + h)) * DD + lc;
        float4 vv = *(const float4*)(v + va);
        Vt[lc + 0][row] = f2bf(vv.x); Vt[lc + 1][row] = f2bf(vv.y);
        Vt[lc + 2][row] = f2bf(vv.z); Vt[lc + 3][row] = f2bf(vv.w);
    }
    __syncthreads();

    // export V^T (swizzled 256B rows)
    {
        char* vtc = (char*)vtg + (size_t)blk * 16384;
        int e = tid >> 2, sq = (tid & 3) * 32;
        #pragma unroll
        for (int k8 = 0; k8 < 4; ++k8) {
            int s = sq + k8 * 8;
            bf16x8 val = *(const bf16x8*)&Vt[e][s];
            *(bf16x8*)(vtc + e * 256 + ((s * 2) ^ ((e & 7) << 4))) = val;
        }
    }

    // MFMA: KV^T[e][d] = sum_s V[s][e] K[s][d]; kz[d] via ones-A
    const int w = tid >> 6, lane = tid & 63, g = lane >> 4, ln = lane & 15;
    bf16x8 av[4];
    #pragma unroll
    for (int ks = 0; ks < 4; ++ks)
        av[ks] = *(const bf16x8*)&Vt[w * 16 + ln][ks * 32 + g * 8];
    bf16x8 ones;
    #pragma unroll
    for (int j = 0; j < 8; ++j) ones[j] = (short)0x3F80;

    float* stc = st + (size_t)blk * STSZ;
    #pragma unroll
    for (int n = 0; n < 4; ++n) {
        f32x4 a = {0.f, 0.f, 0.f, 0.f}, kz4 = {0.f, 0.f, 0.f, 0.f};
        #pragma unroll
        for (int ks = 0; ks < 4; ++ks) {
            bf16x8 bk = *(const bf16x8*)&Kt[n * 16 + ln][ks * 32 + g * 8];
            a = __builtin_amdgcn_mfma_f32_16x16x32_bf16(av[ks], bk, a, 0, 0, 0);
            kz4 = __builtin_amdgcn_mfma_f32_16x16x32_bf16(ones, bk, kz4, 0, 0, 0);
        }
        #pragma unroll
        for (int r = 0; r < 4; ++r)
            stc[(w * 16 + g * 4 + r) * 64 + n * 16 + ln] = a[r];
        if (w == 0 && g == 0) stc[4096 + n * 16 + ln] = kz4[0];
    }
}

// ---------------- Kernel 2 ----------------
__global__ __launch_bounds__(256)
void chunk_scan(const float* __restrict__ st, unsigned short* __restrict__ s0g,
                float* __restrict__ kzg) {
    int flat = blockIdx.x * 256 + threadIdx.x;   // 130*256 = 33280 = 32*1040
    int bh = flat / 1040, i = flat % 1040;
    if (i < 1024) {
        int i4 = i * 4;
        int e = i4 >> 6, d = i4 & 63;
        const float* src = st + (size_t)(bh * NC) * STSZ + i4;
        char* dst = (char*)s0g + (size_t)(bh * NC) * 8192
                    + e * 128 + ((d * 2) ^ ((e & 7) << 4));
        float4 run = {0.f, 0.f, 0.f, 0.f};
        #pragma unroll
        for (int c2 = 0; c2 < NC; ++c2) {
            *(ushort4*)(dst + (size_t)c2 * 8192) =
                make_ushort4(f2bf(run.x), f2bf(run.y), f2bf(run.z), f2bf(run.w));
            float4 x = *(const float4*)(src + (size_t)c2 * STSZ);
            run.x += x.x; run.y += x.y; run.z += x.z; run.w += x.w;
        }
    } else {
        int j = (i - 1024) * 4;   // 0..60
        const float* src = st + (size_t)(bh * NC) * STSZ + 4096 + j;
        float* dst = kzg + (size_t)(bh * NC) * 64 + j;
        float4 run = {0.f, 0.f, 0.f, 0.f};
        #pragma unroll
        for (int c2 = 0; c2 < NC; ++c2) {
            *(float4*)(dst + (size_t)c2 * 64) = run;
            float4 x = *(const float4*)(src + (size_t)c2 * STSZ);
            run.x += x.x; run.y += x.y; run.z += x.z; run.w += x.w;
        }
    }
}

// ---------------- Kernel 3 ----------------
__global__ __launch_bounds__(256, 2)
void lin_attn_out(const float* __restrict__ qk,
                  const unsigned short* __restrict__ kbg,
                  const unsigned short* __restrict__ vtg,
                  const unsigned short* __restrict__ s0g,
                  const float* __restrict__ kzg,
                  float* __restrict__ out) {
    __shared__ __align__(16) char KbL[16384];            // [s][d] swizzled
    __shared__ __align__(16) char VtL[16384];            // [e][s] swizzled
    __shared__ __align__(16) char S0L[8192];             // [e][d] swizzled
    __shared__ float kzl[DD];
    __shared__ __align__(16) unsigned short Wl[4][32][40];
    __shared__ float nul[4][32];

    const int tid = threadIdx.x, blk = blockIdx.x;
    const int bh = blk / NC, c = blk % NC, b = bh / HH, h = bh % HH;
    const int s0 = c * CC;
    const int w = tid >> 6, lane = tid & 63, g = lane >> 4, ln = lane & 15;

    // async stage K, V^T, S0
    {
        const char* kbs = (const char*)kbg + (size_t)blk * 16384;
        const char* vts = (const char*)vtg + (size_t)blk * 16384;
        const char* s0s = (const char*)s0g + (size_t)blk * 8192;
        #pragma unroll
        for (int i = 0; i < 4; ++i) {
            gload16(kbs + w * 4096 + i * 1024 + lane * 16, KbL + w * 4096 + i * 1024);
            gload16(vts + w * 4096 + i * 1024 + lane * 16, VtL + w * 4096 + i * 1024);
        }
        #pragma unroll
        for (int i = 0; i < 2; ++i)
            gload16(s0s + w * 2048 + i * 1024 + lane * 16, S0L + w * 2048 + i * 1024);
        if (tid < DD) kzl[tid] = kzg[(size_t)blk * 64 + tid];
    }

    // q -> registers (phi + bf16)
    bf16x8 aq[2][2];
    #pragma unroll
    for (int m = 0; m < 2; ++m) {
        int tg = s0 + w * 32 + m * 16 + ln;
        const float* qrow = qk + ((size_t)((b * SS + tg) * 2)) * (HH * DD) + h * DD;
        #pragma unroll
        for (int kb2 = 0; kb2 < 2; ++kb2) {
            float4 x0 = *(const float4*)(qrow + kb2 * 32 + g * 8);
            float4 x1 = *(const float4*)(qrow + kb2 * 32 + g * 8 + 4);
            bf16x8 f;
            f[0] = (short)f2bf(phi(x0.x)); f[1] = (short)f2bf(phi(x0.y));
            f[2] = (short)f2bf(phi(x0.z)); f[3] = (short)f2bf(phi(x0.w));
            f[4] = (short)f2bf(phi(x1.x)); f[5] = (short)f2bf(phi(x1.y));
            f[6] = (short)f2bf(phi(x1.z)); f[7] = (short)f2bf(phi(x1.w));
            aq[m][kb2] = f;
        }
    }
    __syncthreads();

    f32x4 O[2][4];
    #pragma unroll
    for (int m = 0; m < 2; ++m)
        #pragma unroll
        for (int n = 0; n < 4; ++n) O[m][n] = (f32x4){0.f, 0.f, 0.f, 0.f};

    // inter-chunk: O += Q * S0  (B-frag from swizzled S0^T)
    #pragma unroll
    for (int n = 0; n < 4; ++n) {
        int e = n * 16 + ln;
        bf16x8 b0 = *(const bf16x8*)(S0L + e * 128 + ((g * 16) ^ ((e & 7) << 4)));
        bf16x8 b1 = *(const bf16x8*)(S0L + e * 128 + ((64 + g * 16) ^ ((e & 7) << 4)));
        #pragma unroll
        for (int m = 0; m < 2; ++m) {
            O[m][n] = __builtin_amdgcn_mfma_f32_16x16x32_bf16(aq[m][0], b0, O[m][n], 0, 0, 0);
            O[m][n] = __builtin_amdgcn_mfma_f32_16x16x32_bf16(aq[m][1], b1, O[m][n], 0, 0, 0);
        }
    }

    // nu base: q . kz
    float nuA[2] = {0.f, 0.f};
    #pragma unroll
    for (int kb2 = 0; kb2 < 2; ++kb2)
        #pragma unroll
        for (int j = 0; j < 8; ++j) {
            float kzv = kzl[kb2 * 32 + g * 8 + j];
            nuA[0] = fmaf(bf2f((unsigned short)aq[0][kb2][j]), kzv, nuA[0]);
            nuA[1] = fmaf(bf2f((unsigned short)aq[1][kb2][j]), kzv, nuA[1]);
        }

    // causal s-block loop
    for (int sblk = 0; sblk <= w; ++sblk) {
        const bool diag = (sblk == w);
        f32x4 Sc[2][2];
        #pragma unroll
        for (int m = 0; m < 2; ++m)
            #pragma unroll
            for (int ns = 0; ns < 2; ++ns) Sc[m][ns] = (f32x4){0.f, 0.f, 0.f, 0.f};

        #pragma unroll
        for (int ns = 0; ns < 2; ++ns) {
            int s = sblk * 32 + ns * 16 + ln;
            const char* srow = KbL + s * 128;
            bf16x8 bk0 = *(const bf16x8*)(srow + ((g * 16) ^ ((s & 7) << 4)));
            bf16x8 bk1 = *(const bf16x8*)(srow + ((64 + g * 16) ^ ((s & 7) << 4)));
            #pragma unroll
            for (int m = 0; m < 2; ++m) {
                Sc[m][ns] = __builtin_amdgcn_mfma_f32_16x16x32_bf16(aq[m][0], bk0, Sc[m][ns], 0, 0, 0);
                Sc[m][ns] = __builtin_amdgcn_mfma_f32_16x16x32_bf16(aq[m][1], bk1, Sc[m][ns], 0, 0, 0);
            }
        }

        // mask + bounce (f32 C-layout -> bf16 A-layout)
        #pragma unroll
        for (int m = 0; m < 2; ++m)
            #pragma unroll
            for (int ns = 0; ns < 2; ++ns)
                #pragma unroll
                for (int r = 0; r < 4; ++r) {
                    int t_loc = m * 16 + g * 4 + r;
                    int s_loc = ns * 16 + ln;
                    float val = Sc[m][ns][r];
                    if (diag && s_loc > t_loc) val = 0.f;
                    Wl[w][t_loc][s_loc] = f2bf(val);
                }
        asm volatile("s_waitcnt lgkmcnt(0)" ::: "memory");
        __builtin_amdgcn_sched_barrier(0);

        bf16x8 bv[4];
        #pragma unroll
        for (int n = 0; n < 4; ++n) {
            int e = n * 16 + ln;
            bv[n] = *(const bf16x8*)(VtL + e * 256 + ((sblk * 64 + g * 16) ^ ((e & 7) << 4)));
        }

        #pragma unroll
        for (int m = 0; m < 2; ++m) {
            bf16x8 pa = *(const bf16x8*)&Wl[w][m * 16 + ln][g * 8];
            float rs = 0.f;
            #pragma unroll
            for (int j = 0; j < 8; ++j) rs += bf2f((unsigned short)pa[j]);
            nuA[m] += rs;
            #pragma unroll
            for (int n = 0; n < 4; ++n)
                O[m][n] = __builtin_amdgcn_mfma_f32_16x16x32_bf16(pa, bv[n], O[m][n], 0, 0, 0);
        }
    }

    // nu reduce + normalize + store
    #pragma unroll
    for (int m = 0; m < 2; ++m) {
        float nt = nuA[m];
        nt += __shfl_xor(nt, 16);
        nt += __shfl_xor(nt, 32);
        if (g == 0) nul[w][m * 16 + ln] = nt;
    }
    asm volatile("s_waitcnt lgkmcnt(0)" ::: "memory");
    __builtin_amdgcn_sched_barrier(0);

    #pragma unroll
    for (int m = 0; m < 2; ++m) {
        float inv[4];
        #pragma unroll
        for (int r = 0; r < 4; ++r) inv[r] = 1.f / nul[w][m * 16 + g * 4 + r];
        #pragma unroll
        for (int n = 0; n < 4; ++n)
            #pragma unroll
            for (int r = 0; r < 4; ++r) {
                int t = w * 32 + m * 16 + g * 4 + r;
                int e = n * 16 + ln;
                size_t oa = ((size_t)((b * SS + s0 + t) * HH + h)) * DD + e;
                out[oa] = O[m][n][r] * inv[r];
            }
    }
}

extern "C" void kernel_launch(void* const* d_in, const int* in_sizes, int n_in,
                              void* d_out, int out_size, void* d_ws, size_t ws_size,
                              hipStream_t stream) {
    const float* qk = (const float*)d_in[0];
    const float* v  = (const float*)d_in[1];
    float* outp = (float*)d_out;

    float* st = (float*)d_ws;
    unsigned short* kbg = (unsigned short*)((char*)d_ws + WS_KB);
    unsigned short* vtg = (unsigned short*)((char*)d_ws + WS_VT);
    unsigned short* s0g = (unsigned short*)((char*)d_ws + WS_S0);
    float* kzg = (float*)((char*)d_ws + WS_KZ);

    prep_state<<<NCHUNK, 256, 0, stream>>>(qk, v, st, kbg, vtg);
    chunk_scan<<<130, 256, 0, stream>>>(st, s0g, kzg);
    lin_attn_out<<<NCHUNK, 256, 0, stream>>>(qk, kbg, vtg, s0g, kzg, outp);
}